// Round 4
// baseline (395.260 us; speedup 1.0000x reference)
//
#include <hip/hip_runtime.h>
#include <hip/hip_bf16.h>
#include <stdint.h>

// EdgeMLP: out[e] = relu(relu(concat(h1[src],h1[dst],h2[src],h2[dst]) @ W0 + b0) @ W1 + b1) @ W2 + b2
// Round 4: single-buffered sA -> 3 blocks/CU (12 waves/CU), 2 barriers/tile,
// deferred out-write overlapped with next tile's layer 0. Swapped-operand MFMA,
// register-resident weights (wave N-split), global_load_lds gather with
// both-sides XOR swizzle.

typedef __attribute__((ext_vector_type(8))) __bf16 bf16x8;
typedef __attribute__((ext_vector_type(4))) __bf16 bf16x4;
typedef __attribute__((ext_vector_type(4))) float  floatx4;

__device__ inline floatx4 mfma16x16x32(bf16x8 a, bf16x8 b, floatx4 c) {
  return __builtin_amdgcn_mfma_f32_16x16x32_bf16(a, b, c, 0, 0, 0);
}

__device__ inline void bar_lds() {
  asm volatile("s_waitcnt lgkmcnt(0)" ::: "memory");
  __builtin_amdgcn_s_barrier();
}

// ---- prep: f32 -> bf16 node feature tables ----
__global__ void cvt_nodes_kernel(const float* __restrict__ h1,
                                 const float* __restrict__ h2,
                                 __bf16* __restrict__ hb1,
                                 __bf16* __restrict__ hb2, int n4) {
  const int stride = gridDim.x * blockDim.x;
  for (int i = blockIdx.x * blockDim.x + threadIdx.x; i < 2 * n4; i += stride) {
    const bool second = i >= n4;
    const int j = second ? i - n4 : i;
    const float4 v = reinterpret_cast<const float4*>(second ? h2 : h1)[j];
    bf16x4 o;
    o[0] = (__bf16)v.x; o[1] = (__bf16)v.y; o[2] = (__bf16)v.z; o[3] = (__bf16)v.w;
    reinterpret_cast<bf16x4*>(second ? hb2 : hb1)[j] = o;
  }
}

// ---- prep: transpose weights to bf16 [N][K] ----
__global__ void cvt_w_kernel(const float* __restrict__ W0, const float* __restrict__ W1,
                             __bf16* __restrict__ W0T, __bf16* __restrict__ W1T) {
  const int t = blockIdx.x * 256 + threadIdx.x;
  if (t < 128 * 256) {                 // W0T[n][k] = W0[k][n]
    const int n = t >> 8, k = t & 255;
    W0T[t] = (__bf16)W0[k * 128 + n];
  } else {
    const int t2 = t - 128 * 256;      // W1T[n][k] = W1[k][n]
    const int n = t2 >> 7, k = t2 & 127;
    W1T[t2] = (__bf16)W1[k * 128 + n];
  }
}

// ---- main kernel ----
__global__ __launch_bounds__(256, 3)
void edge_mlp_kernel(const __bf16* __restrict__ hb1, const __bf16* __restrict__ hb2,
                     const int* __restrict__ srcI, const int* __restrict__ dstI,
                     const __bf16* __restrict__ W0T, const float* __restrict__ b0,
                     const __bf16* __restrict__ W1T, const float* __restrict__ b1,
                     const float* __restrict__ W2, const float* __restrict__ b2,
                     float* __restrict__ out, int E, int nTiles) {
  // sA: [64 edges][256 feats] bf16, row stride 512 B. Linear for global_load_lds;
  // logical 16B chunk c of row e stored at phys chunk c^(e&7); reads XOR with (e&7)<<4.
  // sH: [64][128] bf16, row stride 256 B, same XOR swizzle.
  // sRed: [64 edges][4 waves] f32 layer-2 partials (16B rows -> float4 read).
  __shared__ char sA[64 * 512];
  __shared__ char sH[64 * 256];
  __shared__ float sRed[64][4];

  const int tid  = threadIdx.x;
  const int lane = tid & 63;
  const int l15  = lane & 15;
  const int hi   = lane >> 4;
  const int hi16 = hi * 16;
  const int wvU  = __builtin_amdgcn_readfirstlane(tid >> 6);  // wave id (uniform)
  const int wv16 = wvU * 16;
  const int wvByte = wvU * 8192;

  // gather role of this lane
  const int lhalf = lane >> 5;          // which of the 2 edges per issue
  const int sseg  = (lane >> 3) & 3;    // 0=h1[src] 1=h1[dst] 2=h2[src] 3=h2[dst]
  const int* idxTab = (sseg & 1) ? dstI : srcI;
  const __bf16* segBase = (sseg < 2) ? hb1 : hb2;

  // ---- per-wave register-resident weights (N-split: cols [32*wv, 32*wv+32)) ----
  const int col0 = wvU * 32 + l15;
  const int col1 = col0 + 16;
  bf16x8 w0f[8][2];
  const bf16x8* w0p = reinterpret_cast<const bf16x8*>(W0T);
#pragma unroll
  for (int kk = 0; kk < 8; ++kk) {
    w0f[kk][0] = w0p[col0 * 32 + kk * 4 + hi];
    w0f[kk][1] = w0p[col1 * 32 + kk * 4 + hi];
  }
  bf16x8 w1f[4][2];
  const bf16x8* w1p = reinterpret_cast<const bf16x8*>(W1T);
#pragma unroll
  for (int kk = 0; kk < 4; ++kk) {
    w1f[kk][0] = w1p[col0 * 16 + kk * 4 + hi];
    w1f[kk][1] = w1p[col1 * 16 + kk * 4 + hi];
  }
  // per-lane n-constants for transposed C-layout: n = wv*32 + nt*16 + hi*4 + r
  float b0c[2][4], b1c[2][4], w2c[2][4];
#pragma unroll
  for (int nt = 0; nt < 2; ++nt) {
#pragma unroll
    for (int r = 0; r < 4; ++r) {
      const int n = wvU * 32 + nt * 16 + hi * 4 + r;
      b0c[nt][r] = b0[n];
      b1c[nt][r] = b1[n];
      w2c[nt][r] = W2[n];
    }
  }
  const float b2v = b2[0];

  const int tstride = gridDim.x;

  auto loadIdx = [&](int (&d)[8], int tt2) {
    const bool valid = tt2 < nTiles;
#pragma unroll
    for (int i = 0; i < 8; ++i) {
      const int eLoc = wv16 + i * 2 + lhalf;
      const int ge = tt2 * 64 + eLoc;
      d[i] = (valid && ge < E) ? idxTab[ge] : 0;
    }
  };

  auto issueGather = [&](const int (&idx8)[8]) {
#pragma unroll
    for (int i = 0; i < 8; ++i) {
      const int eLoc = wv16 + i * 2 + lhalf;
      const int c = (lane & 7) ^ (eLoc & 7);
      const __bf16* g = segBase + (size_t)idx8[i] * 64 + c * 8;
      char* l = sA + wvByte + i * 1024;  // + lane*16 added by HW
      __builtin_amdgcn_global_load_lds(
          (const __attribute__((address_space(1))) void*)g,
          (__attribute__((address_space(3))) void*)l, 16, 0, 0);
    }
  };

  // ---- prologue ----
  const int tile0 = blockIdx.x;
  int idxNext[8];
  {
    int idx0[8];
    loadIdx(idx0, tile0);
    issueGather(idx0);                  // gathers for first tile
  }
  loadIdx(idxNext, tile0 + tstride);
  int prevBase = -1;

  for (int tt = tile0; tt < nTiles; tt += tstride) {
    __syncthreads();  // drains vmcnt: sA(t) ready; sRed(t-1) + sH reuse ordered

    // ---- deferred out-write for previous tile (overlaps layer 0) ----
    if (prevBase >= 0 && lane < 16) {
      const int e = wv16 + l15;
      const int ge = prevBase + e;
      if (ge < E) {
        const float4 v = *reinterpret_cast<const float4*>(&sRed[e][0]);
        out[ge] = v.x + v.y + v.z + v.w + b2v;
      }
    }

    // ---- layer 0 (swapped): accT col=edge, row=n ----
    floatx4 accT[4][2];
#pragma unroll
    for (int mt = 0; mt < 4; ++mt) { accT[mt][0] = (floatx4)0.f; accT[mt][1] = (floatx4)0.f; }
#pragma unroll
    for (int kk = 0; kk < 8; ++kk) {
#pragma unroll
      for (int mt = 0; mt < 4; ++mt) {
        const int row = mt * 16 + l15;   // edge within tile (B-frag col)
        const bf16x8 a = *reinterpret_cast<const bf16x8*>(
            sA + row * 512 + ((kk * 64 + hi16) ^ ((row & 7) << 4)));
        accT[mt][0] = mfma16x16x32(w0f[kk][0], a, accT[mt][0]);
        accT[mt][1] = mfma16x16x32(w0f[kk][1], a, accT[mt][1]);
      }
    }

    // bias + relu -> sH: lane holds 4 contiguous n for edge mt*16+l15 -> 8B writes
#pragma unroll
    for (int mt = 0; mt < 4; ++mt) {
      const int e = mt * 16 + l15;
      char* rowp = sH + e * 256;
      const int swz = (e & 7) << 4;
#pragma unroll
      for (int nt = 0; nt < 2; ++nt) {
        bf16x4 pk;
#pragma unroll
        for (int r = 0; r < 4; ++r)
          pk[r] = (__bf16)fmaxf(accT[mt][nt][r] + b0c[nt][r], 0.0f);
        const int nb = wvU * 64 + nt * 32 + hi * 8;  // byte offset of n0 within row
        *reinterpret_cast<bf16x4*>(rowp + (nb ^ swz)) = pk;
      }
    }
    bar_lds();  // B2: sA fully consumed, sH visible

    // ---- issue gathers for t+1 into sA (lands during layer 1 + tail) ----
    if (tt + tstride < nTiles) issueGather(idxNext);
    loadIdx(idxNext, tt + 2 * tstride);

    // ---- layer 1 (swapped): acc2T col=edge, row=n ----
    floatx4 acc2T[4][2];
#pragma unroll
    for (int mt = 0; mt < 4; ++mt) { acc2T[mt][0] = (floatx4)0.f; acc2T[mt][1] = (floatx4)0.f; }
#pragma unroll
    for (int kk = 0; kk < 4; ++kk) {
#pragma unroll
      for (int mt = 0; mt < 4; ++mt) {
        const int row = mt * 16 + l15;
        const bf16x8 a = *reinterpret_cast<const bf16x8*>(
            sH + row * 256 + ((kk * 64 + hi16) ^ ((row & 7) << 4)));
        acc2T[mt][0] = mfma16x16x32(w1f[kk][0], a, acc2T[mt][0]);
        acc2T[mt][1] = mfma16x16x32(w1f[kk][1], a, acc2T[mt][1]);
      }
    }

    // ---- layer 2: per-lane dot over 8 n, reduce across hi-groups -> sRed ----
#pragma unroll
    for (int mt = 0; mt < 4; ++mt) {
      float p = 0.f;
#pragma unroll
      for (int nt = 0; nt < 2; ++nt)
#pragma unroll
        for (int r = 0; r < 4; ++r)
          p += fmaxf(acc2T[mt][nt][r] + b1c[nt][r], 0.0f) * w2c[nt][r];
      p += __shfl_xor(p, 16);
      p += __shfl_xor(p, 32);
      if (lane < 16) sRed[mt * 16 + l15][wvU] = p;  // no barrier: next top sync orders
    }

    prevBase = tt * 64;
  }

  // ---- final deferred out-write ----
  __syncthreads();
  if (prevBase >= 0 && lane < 16) {
    const int e = wv16 + l15;
    const int ge = prevBase + e;
    if (ge < E) {
      const float4 v = *reinterpret_cast<const float4*>(&sRed[e][0]);
      out[ge] = v.x + v.y + v.z + v.w + b2v;
    }
  }
}

// ---- correctness fallback (only if workspace too small for bf16 tables) ----
__global__ void edge_mlp_fallback(const float* __restrict__ h1, const float* __restrict__ h2,
                                  const int* __restrict__ src, const int* __restrict__ dst,
                                  const float* __restrict__ W0, const float* __restrict__ b0,
                                  const float* __restrict__ W1, const float* __restrict__ b1,
                                  const float* __restrict__ W2, const float* __restrict__ b2,
                                  float* __restrict__ out, int E) {
  __shared__ float sa[256];
  __shared__ float sh[128];
  __shared__ float sr[128];
  const int e = blockIdx.x;
  if (e >= E) return;
  const int t = threadIdx.x;  // 128 threads
  const int is = src[e], id = dst[e];
  if (t < 64) { sa[t] = h1[is * 64 + t]; sa[128 + t] = h2[is * 64 + t]; }
  else { const int u = t - 64; sa[64 + u] = h1[id * 64 + u]; sa[192 + u] = h2[id * 64 + u]; }
  __syncthreads();
  float a0 = b0[t];
  for (int k = 0; k < 256; ++k) a0 += sa[k] * W0[k * 128 + t];
  sh[t] = fmaxf(a0, 0.f);
  __syncthreads();
  float a1 = b1[t];
  for (int k = 0; k < 128; ++k) a1 += sh[k] * W1[k * 128 + t];
  sr[t] = fmaxf(a1, 0.f) * W2[t];
  __syncthreads();
  if (t == 0) {
    float s = b2[0];
    for (int k = 0; k < 128; ++k) s += sr[k];
    out[e] = s;
  }
}

extern "C" void kernel_launch(void* const* d_in, const int* in_sizes, int n_in,
                              void* d_out, int out_size, void* d_ws, size_t ws_size,
                              hipStream_t stream) {
  const float* h1 = (const float*)d_in[0];
  const float* h2 = (const float*)d_in[1];
  const int* src = (const int*)d_in[2];
  const int* dst = (const int*)d_in[3];
  const float* W0 = (const float*)d_in[4];
  const float* b0 = (const float*)d_in[5];
  const float* W1 = (const float*)d_in[6];
  const float* b1 = (const float*)d_in[7];
  const float* W2 = (const float*)d_in[8];
  const float* b2 = (const float*)d_in[9];
  float* out = (float*)d_out;

  const int D = 64;
  const int nNodes = in_sizes[0] / D;
  const int E = in_sizes[2];

  char* ws = (char*)d_ws;
  __bf16* W0T = (__bf16*)(ws);             // 65536 B
  __bf16* W1T = (__bf16*)(ws + 65536);     // 32768 B
  __bf16* hb1 = (__bf16*)(ws + 98304);
  const size_t hbBytes = (size_t)nNodes * D * sizeof(__bf16);
  __bf16* hb2 = (__bf16*)(ws + 98304 + hbBytes);
  const bool useBT = ws_size >= 98304 + 2 * hbBytes;

  if (!useBT) {
    edge_mlp_fallback<<<dim3(E), dim3(128), 0, stream>>>(
        h1, h2, src, dst, W0, b0, W1, b1, W2, b2, out, E);
    return;
  }

  cvt_w_kernel<<<dim3(192), dim3(256), 0, stream>>>(W0, W1, W0T, W1T);
  {
    const int n4 = nNodes * D / 4;
    int blocks = (2 * n4 + 255) / 256;
    if (blocks > 2048) blocks = 2048;
    cvt_nodes_kernel<<<dim3(blocks), dim3(256), 0, stream>>>(h1, h2, hb1, hb2, n4);
  }

  const int nTiles = (E + 63) / 64;
  const int grid = nTiles < 768 ? nTiles : 768;  // 3 blocks/CU resident
  edge_mlp_kernel<<<dim3(grid), dim3(256), 0, stream>>>(
      hb1, hb2, src, dst, W0T, b0, W1T, b1, W2, b2, out, E, nTiles);
}

// Round 5
// 168.069 us; speedup vs baseline: 2.3518x; 2.3518x over previous
//
#include <hip/hip_runtime.h>
#include <hip/hip_bf16.h>
#include <stdint.h>

// EdgeMLP: out[e] = relu(relu(concat(h1[src],h1[dst],h2[src],h2[dst]) @ W0 + b0) @ W1 + b1) @ W2 + b2
// Round 5: algebraic split of layer 0 into per-node precompute:
//   u[v] = W0[0:64]^T h1[v] + W0[128:192]^T h2[v] + b0   (src part)
//   w[v] = W0[64:128]^T h1[v] + W0[192:256]^T h2[v]       (dst part)
//   y0[e] = relu(u[src[e]] + w[dst[e]])
// Edge kernel keeps R3's proven memory structure: global_load_lds dbuf gather
// (64 edges x 512B rows, both-sides XOR swizzle), 80KB LDS, 2 blocks/CU,
// 3 barriers/tile. Only layer-1 MFMA remains per edge.

typedef __attribute__((ext_vector_type(8))) __bf16 bf16x8;
typedef __attribute__((ext_vector_type(4))) __bf16 bf16x4;
typedef __attribute__((ext_vector_type(4))) float  floatx4;

__device__ inline floatx4 mfma16x16x32(bf16x8 a, bf16x8 b, floatx4 c) {
  return __builtin_amdgcn_mfma_f32_16x16x32_bf16(a, b, c, 0, 0, 0);
}

__device__ inline void bar_lds() {
  asm volatile("s_waitcnt lgkmcnt(0)" ::: "memory");
  __builtin_amdgcn_s_barrier();
}

// ---- prep: weight transforms (bf16, n-major) ----
// W1T[n][k] = W1[k][n]                         (128x128)
// W0uT[n][k2] = k2<64 ? W0[k2][n]    : W0[64+k2][n]    (128x128; h1|h2 src rows)
// W0wT[n][k2] = k2<64 ? W0[64+k2][n] : W0[128+k2][n]   (128x128; h1|h2 dst rows)
__global__ void cvt_w_kernel(const float* __restrict__ W0, const float* __restrict__ W1,
                             __bf16* __restrict__ W1T, __bf16* __restrict__ W0uT,
                             __bf16* __restrict__ W0wT) {
  const int t = blockIdx.x * 256 + threadIdx.x;  // 192 blocks * 256 = 49152
  if (t < 16384) {
    const int n = t >> 7, k = t & 127;
    W1T[t] = (__bf16)W1[k * 128 + n];
  } else if (t < 32768) {
    const int t2 = t - 16384;
    const int n = t2 >> 7, k2 = t2 & 127;
    const int row = (k2 < 64) ? k2 : 64 + k2;
    W0uT[t2] = (__bf16)W0[row * 128 + n];
  } else {
    const int t3 = t - 32768;
    const int n = t3 >> 7, k2 = t3 & 127;
    const int row = (k2 < 64) ? 64 + k2 : 128 + k2;
    W0wT[t3] = (__bf16)W0[row * 128 + n];
  }
}

// ---- node phase: u/w tables, 64 nodes per block ----
__global__ __launch_bounds__(256, 2)
void node_uw_kernel(const float* __restrict__ h1, const float* __restrict__ h2,
                    const __bf16* __restrict__ W0uT, const __bf16* __restrict__ W0wT,
                    const float* __restrict__ b0,
                    __bf16* __restrict__ uTab, __bf16* __restrict__ wTab, int nNodes) {
  __shared__ char sN[64 * 256];  // [64 nodes][128 k2] bf16, XOR-swizzled rows
  const int tid = threadIdx.x;
  const int base = blockIdx.x * 64;

  {  // stage: thread -> (row r, 4 chunks of 16B)
    const int r = tid >> 2, q = tid & 3;
    const int node = base + r;
    const int swz = (r & 7) << 4;
#pragma unroll
    for (int ii = 0; ii < 4; ++ii) {
      const int c = q * 4 + ii;  // 16 chunks of 16B per 256B row
      bf16x8 v;
      if (node < nNodes) {
        const float* sp = (c < 8) ? (h1 + (size_t)node * 64 + c * 8)
                                  : (h2 + (size_t)node * 64 + (c - 8) * 8);
        const float4 x = reinterpret_cast<const float4*>(sp)[0];
        const float4 y = reinterpret_cast<const float4*>(sp)[1];
        v[0] = (__bf16)x.x; v[1] = (__bf16)x.y; v[2] = (__bf16)x.z; v[3] = (__bf16)x.w;
        v[4] = (__bf16)y.x; v[5] = (__bf16)y.y; v[6] = (__bf16)y.z; v[7] = (__bf16)y.w;
      } else {
#pragma unroll
        for (int k = 0; k < 8; ++k) v[k] = (__bf16)0.f;
      }
      *reinterpret_cast<bf16x8*>(sN + r * 256 + ((c * 16) ^ swz)) = v;
    }
  }
  __syncthreads();

  const int lane = tid & 63;
  const int l15 = lane & 15;
  const int hi = lane >> 4;
  const int hi16 = hi * 16;
  const int wvU = __builtin_amdgcn_readfirstlane(tid >> 6);

  float b0c[2][4];
#pragma unroll
  for (int nt = 0; nt < 2; ++nt)
#pragma unroll
    for (int r = 0; r < 4; ++r) b0c[nt][r] = b0[wvU * 32 + nt * 16 + hi * 4 + r];

#pragma unroll
  for (int pass = 0; pass < 2; ++pass) {
    const __bf16* Wt = pass ? W0wT : W0uT;
    __bf16* Tab = pass ? wTab : uTab;
    const bf16x8* wp = reinterpret_cast<const bf16x8*>(Wt);
    bf16x8 wf[4][2];
#pragma unroll
    for (int kk = 0; kk < 4; ++kk) {
      wf[kk][0] = wp[(wvU * 32 + l15) * 16 + kk * 4 + hi];
      wf[kk][1] = wp[(wvU * 32 + 16 + l15) * 16 + kk * 4 + hi];
    }
    floatx4 acc[4][2];
#pragma unroll
    for (int mt = 0; mt < 4; ++mt) { acc[mt][0] = (floatx4)0.f; acc[mt][1] = (floatx4)0.f; }
#pragma unroll
    for (int kk = 0; kk < 4; ++kk) {
#pragma unroll
      for (int mt = 0; mt < 4; ++mt) {
        const int row = mt * 16 + l15;
        const bf16x8 a = *reinterpret_cast<const bf16x8*>(
            sN + row * 256 + ((kk * 64 + hi16) ^ ((row & 7) << 4)));
        acc[mt][0] = mfma16x16x32(wf[kk][0], a, acc[mt][0]);
        acc[mt][1] = mfma16x16x32(wf[kk][1], a, acc[mt][1]);
      }
    }
#pragma unroll
    for (int mt = 0; mt < 4; ++mt) {
      const int node = base + mt * 16 + l15;
      if (node < nNodes) {
#pragma unroll
        for (int nt = 0; nt < 2; ++nt) {
          bf16x4 pk;
#pragma unroll
          for (int r = 0; r < 4; ++r) {
            const float v = acc[mt][nt][r] + (pass ? 0.f : b0c[nt][r]);
            pk[r] = (__bf16)v;
          }
          *reinterpret_cast<bf16x4*>(Tab + (size_t)node * 128 + wvU * 32 + nt * 16 +
                                     hi * 4) = pk;
        }
      }
    }
  }
}

// ---- edge kernel ----
__global__ __launch_bounds__(256, 2)
void edge_uw_kernel(const __bf16* __restrict__ uTab, const __bf16* __restrict__ wTab,
                    const int* __restrict__ srcI, const int* __restrict__ dstI,
                    const __bf16* __restrict__ W1T, const float* __restrict__ b1,
                    const float* __restrict__ W2, const float* __restrict__ b2,
                    float* __restrict__ out, int E, int nTiles) {
  // sUW: 2 x [64 edges][512B] (u-row 256B ++ w-row 256B), double-buffered,
  //      linear dest for global_load_lds; logical 16B chunk j of row e stored at
  //      phys chunk (j&24)|((j&7)^(e&7)); reads XOR byte offset with (e&7)<<4.
  // sH : [64][128] bf16 rows of relu(u+w), 256B rows, same XOR swizzle.
  // sRed: overlay on head of consumed sUW[cur] (layer-2 partials, 1KB).
  __shared__ char sUW[2 * 64 * 512];
  __shared__ char sH[64 * 256];

  const int tid = threadIdx.x;
  const int lane = tid & 63;
  const int l15 = lane & 15;
  const int hi = lane >> 4;
  const int hi16 = hi * 16;
  const int wvU = __builtin_amdgcn_readfirstlane(tid >> 6);
  const int wv16 = wvU * 16;
  const int wvByte = wvU * 8192;

  // gather role: phys chunk p = lane&31 of edge (wv16 + i*2 + lane>>5)
  const int lhalf = lane >> 5;
  const int p31 = lane & 31;
  const int half = (p31 >> 4) & 1;             // 0 -> u[src], 1 -> w[dst]
  const int* gIdxTab = half ? dstI : srcI;
  const __bf16* gTab = half ? wTab : uTab;

  // ---- per-wave register weights: W1T cols [32*wv, 32*wv+32) ----
  bf16x8 w1f[4][2];
  const bf16x8* w1p = reinterpret_cast<const bf16x8*>(W1T);
#pragma unroll
  for (int kk = 0; kk < 4; ++kk) {
    w1f[kk][0] = w1p[(wvU * 32 + l15) * 16 + kk * 4 + hi];
    w1f[kk][1] = w1p[(wvU * 32 + 16 + l15) * 16 + kk * 4 + hi];
  }
  float b1c[2][4], w2c[2][4];
#pragma unroll
  for (int nt = 0; nt < 2; ++nt)
#pragma unroll
    for (int r = 0; r < 4; ++r) {
      const int n = wvU * 32 + nt * 16 + hi * 4 + r;
      b1c[nt][r] = b1[n];
      w2c[nt][r] = W2[n];
    }
  const float b2v = b2[0];

  const int tstride = gridDim.x;

  auto loadIdx = [&](int (&d)[8], int tt2) {
    const bool valid = tt2 < nTiles;
#pragma unroll
    for (int i = 0; i < 8; ++i) {
      const int eLoc = wv16 + i * 2 + lhalf;
      const int ge = tt2 * 64 + eLoc;
      d[i] = (valid && ge < E) ? gIdxTab[ge] : 0;
    }
  };

  auto issueGather = [&](int nb, const int (&idx8)[8]) {
#pragma unroll
    for (int i = 0; i < 8; ++i) {
      const int eLoc = wv16 + i * 2 + lhalf;
      // logical within-half chunk for this lane's phys slot
      const int wc = (p31 & 8) | ((p31 & 7) ^ (eLoc & 7));
      const __bf16* g = gTab + (size_t)idx8[i] * 128 + (wc & 15) * 8;
      char* l = sUW + nb * 32768 + wvByte + i * 1024;  // + lane*16 added by HW
      __builtin_amdgcn_global_load_lds(
          (const __attribute__((address_space(1))) void*)g,
          (__attribute__((address_space(3))) void*)l, 16, 0, 0);
    }
  };

  // ---- prologue ----
  const int tile0 = blockIdx.x;
  int idxA[8], idxB[8];
  loadIdx(idxA, tile0);
  issueGather(0, idxA);
  loadIdx(idxB, tile0 + tstride);
  int cur = 0;

  for (int tt = tile0; tt < nTiles; tt += tstride) {
    __syncthreads();  // drains vmcnt: sUW[cur] ready; orders sH/sRed reuse

    // prefetch next tile's gathers (other buffer) + next-next indices
    if (tt + tstride < nTiles) issueGather(cur ^ 1, idxB);
    loadIdx(idxA, tt + 2 * tstride);

    const char* sUWc = sUW + cur * 32768;

    // ---- "layer 0": h = relu(u[src] + w[dst]) -> sH ----
    {
      const int aR = wv16 + (lane >> 2);  // this wave's 16 rows
      const int acq = lane & 3;
      const int aswz = (aR & 7) << 4;
      const char* rowU = sUWc + aR * 512;
      char* rowH = sH + aR * 256;
#pragma unroll
      for (int ii = 0; ii < 4; ++ii) {
        const int c = acq * 4 + ii;           // 16B chunk 0..15
        const int off = (c * 16) ^ aswz;
        const bf16x8 uu = *reinterpret_cast<const bf16x8*>(rowU + off);
        const bf16x8 ww = *reinterpret_cast<const bf16x8*>(rowU + 256 + off);
        bf16x8 hh;
#pragma unroll
        for (int k = 0; k < 8; ++k)
          hh[k] = (__bf16)fmaxf((float)uu[k] + (float)ww[k], 0.0f);
        *reinterpret_cast<bf16x8*>(rowH + off) = hh;
      }
    }
    bar_lds();  // B2: sUW[cur] consumed, sH visible

    // ---- layer 1 (swapped): acc2T col=edge, row=n ----
    floatx4 acc2T[4][2];
#pragma unroll
    for (int mt = 0; mt < 4; ++mt) { acc2T[mt][0] = (floatx4)0.f; acc2T[mt][1] = (floatx4)0.f; }
#pragma unroll
    for (int kk = 0; kk < 4; ++kk) {
#pragma unroll
      for (int mt = 0; mt < 4; ++mt) {
        const int row = mt * 16 + l15;
        const bf16x8 a = *reinterpret_cast<const bf16x8*>(
            sH + row * 256 + ((kk * 64 + hi16) ^ ((row & 7) << 4)));
        acc2T[mt][0] = mfma16x16x32(w1f[kk][0], a, acc2T[mt][0]);
        acc2T[mt][1] = mfma16x16x32(w1f[kk][1], a, acc2T[mt][1]);
      }
    }

    // ---- layer 2: per-lane dot over 8 n, reduce across hi groups ----
    float* sRedF = (float*)sUWc;  // overlay on consumed sUW[cur]
#pragma unroll
    for (int mt = 0; mt < 4; ++mt) {
      float pp = 0.f;
#pragma unroll
      for (int nt = 0; nt < 2; ++nt)
#pragma unroll
        for (int r = 0; r < 4; ++r)
          pp += fmaxf(acc2T[mt][nt][r] + b1c[nt][r], 0.0f) * w2c[nt][r];
      pp += __shfl_xor(pp, 16);
      pp += __shfl_xor(pp, 32);
      if (lane < 16) sRedF[wvU * 64 + mt * 16 + l15] = pp;
    }
    bar_lds();  // B3: partials visible

    if (tid < 64) {
      const int ge = tt * 64 + tid;
      if (ge < E) {
        out[ge] = sRedF[tid] + sRedF[64 + tid] + sRedF[128 + tid] +
                  sRedF[192 + tid] + b2v;
      }
    }

#pragma unroll
    for (int i = 0; i < 8; ++i) idxB[i] = idxA[i];
    cur ^= 1;
  }
}

// ---- correctness fallback (only if workspace too small) ----
__global__ void edge_mlp_fallback(const float* __restrict__ h1, const float* __restrict__ h2,
                                  const int* __restrict__ src, const int* __restrict__ dst,
                                  const float* __restrict__ W0, const float* __restrict__ b0,
                                  const float* __restrict__ W1, const float* __restrict__ b1,
                                  const float* __restrict__ W2, const float* __restrict__ b2,
                                  float* __restrict__ out, int E) {
  __shared__ float sa[256];
  __shared__ float sh[128];
  __shared__ float sr[128];
  const int e = blockIdx.x;
  if (e >= E) return;
  const int t = threadIdx.x;  // 128 threads
  const int is = src[e], id = dst[e];
  if (t < 64) { sa[t] = h1[is * 64 + t]; sa[128 + t] = h2[is * 64 + t]; }
  else { const int u = t - 64; sa[64 + u] = h1[id * 64 + u]; sa[192 + u] = h2[id * 64 + u]; }
  __syncthreads();
  float a0 = b0[t];
  for (int k = 0; k < 256; ++k) a0 += sa[k] * W0[k * 128 + t];
  sh[t] = fmaxf(a0, 0.f);
  __syncthreads();
  float a1 = b1[t];
  for (int k = 0; k < 128; ++k) a1 += sh[k] * W1[k * 128 + t];
  sr[t] = fmaxf(a1, 0.f) * W2[t];
  __syncthreads();
  if (t == 0) {
    float s = b2[0];
    for (int k = 0; k < 128; ++k) s += sr[k];
    out[e] = s;
  }
}

extern "C" void kernel_launch(void* const* d_in, const int* in_sizes, int n_in,
                              void* d_out, int out_size, void* d_ws, size_t ws_size,
                              hipStream_t stream) {
  const float* h1 = (const float*)d_in[0];
  const float* h2 = (const float*)d_in[1];
  const int* src = (const int*)d_in[2];
  const int* dst = (const int*)d_in[3];
  const float* W0 = (const float*)d_in[4];
  const float* b0 = (const float*)d_in[5];
  const float* W1 = (const float*)d_in[6];
  const float* b1 = (const float*)d_in[7];
  const float* W2 = (const float*)d_in[8];
  const float* b2 = (const float*)d_in[9];
  float* out = (float*)d_out;

  const int D = 64;
  const int nNodes = in_sizes[0] / D;
  const int E = in_sizes[2];

  char* ws = (char*)d_ws;
  __bf16* W1T = (__bf16*)(ws);                 // 32768 B
  __bf16* W0uT = (__bf16*)(ws + 32768);        // 32768 B
  __bf16* W0wT = (__bf16*)(ws + 65536);        // 32768 B
  const size_t tabBytes = (size_t)nNodes * 128 * sizeof(__bf16);
  __bf16* uTab = (__bf16*)(ws + 98304);
  __bf16* wTab = (__bf16*)(ws + 98304 + tabBytes);
  const bool useFast = ws_size >= 98304 + 2 * tabBytes;

  if (!useFast) {
    edge_mlp_fallback<<<dim3(E), dim3(128), 0, stream>>>(
        h1, h2, src, dst, W0, b0, W1, b1, W2, b2, out, E);
    return;
  }

  cvt_w_kernel<<<dim3(192), dim3(256), 0, stream>>>(W0, W1, W1T, W0uT, W0wT);
  node_uw_kernel<<<dim3((nNodes + 63) / 64), dim3(256), 0, stream>>>(
      h1, h2, W0uT, W0wT, b0, uTab, wTab, nNodes);

  const int nTiles = (E + 63) / 64;
  const int grid = nTiles < 1024 ? nTiles : 1024;
  edge_uw_kernel<<<dim3(grid), dim3(256), 0, stream>>>(
      uTab, wTab, src, dst, W1T, b1, W2, b2, out, E, nTiles);
}

// Round 6
// 151.709 us; speedup vs baseline: 2.6054x; 1.1078x over previous
//
#include <hip/hip_runtime.h>
#include <hip/hip_bf16.h>
#include <stdint.h>

// EdgeMLP: out[e] = relu(relu(concat(h1[src],h1[dst],h2[src],h2[dst]) @ W0 + b0) @ W1 + b1) @ W2 + b2
// Round 6: layer-0 algebraic split (per-node u/w tables) + 512-thread edge
// blocks (8 waves = 2M x 4N) at the same 80KB LDS -> 4 waves/SIMD instead of 2.
// Memory structure unchanged from R5: global_load_lds dbuf gather, both-sides
// XOR swizzle, 3 barriers/tile.

typedef __attribute__((ext_vector_type(8))) __bf16 bf16x8;
typedef __attribute__((ext_vector_type(4))) __bf16 bf16x4;
typedef __attribute__((ext_vector_type(4))) float  floatx4;

__device__ inline floatx4 mfma16x16x32(bf16x8 a, bf16x8 b, floatx4 c) {
  return __builtin_amdgcn_mfma_f32_16x16x32_bf16(a, b, c, 0, 0, 0);
}

__device__ inline void bar_lds() {
  asm volatile("s_waitcnt lgkmcnt(0)" ::: "memory");
  __builtin_amdgcn_s_barrier();
}

// ---- prep: weight transforms (bf16, n-major) ----
__global__ void cvt_w_kernel(const float* __restrict__ W0, const float* __restrict__ W1,
                             __bf16* __restrict__ W1T, __bf16* __restrict__ W0uT,
                             __bf16* __restrict__ W0wT) {
  const int t = blockIdx.x * 256 + threadIdx.x;  // 192 * 256 = 49152
  if (t < 16384) {
    const int n = t >> 7, k = t & 127;
    W1T[t] = (__bf16)W1[k * 128 + n];
  } else if (t < 32768) {
    const int t2 = t - 16384;
    const int n = t2 >> 7, k2 = t2 & 127;
    const int row = (k2 < 64) ? k2 : 64 + k2;        // h1 | h2 src rows
    W0uT[t2] = (__bf16)W0[row * 128 + n];
  } else {
    const int t3 = t - 32768;
    const int n = t3 >> 7, k2 = t3 & 127;
    const int row = (k2 < 64) ? 64 + k2 : 128 + k2;  // h1 | h2 dst rows
    W0wT[t3] = (__bf16)W0[row * 128 + n];
  }
}

// ---- node phase: u[v] = W0u^T [h1|h2](v) + b0 ; w[v] = W0w^T [h1|h2](v) ----
__global__ __launch_bounds__(256, 2)
void node_uw_kernel(const float* __restrict__ h1, const float* __restrict__ h2,
                    const __bf16* __restrict__ W0uT, const __bf16* __restrict__ W0wT,
                    const float* __restrict__ b0,
                    __bf16* __restrict__ uTab, __bf16* __restrict__ wTab, int nNodes) {
  __shared__ char sN[64 * 256];  // [64 nodes][128 k2] bf16, XOR-swizzled rows
  const int tid = threadIdx.x;
  const int base = blockIdx.x * 64;

  {  // stage
    const int r = tid >> 2, q = tid & 3;
    const int node = base + r;
    const int swz = (r & 7) << 4;
#pragma unroll
    for (int ii = 0; ii < 4; ++ii) {
      const int c = q * 4 + ii;
      bf16x8 v;
      if (node < nNodes) {
        const float* sp = (c < 8) ? (h1 + (size_t)node * 64 + c * 8)
                                  : (h2 + (size_t)node * 64 + (c - 8) * 8);
        const float4 x = reinterpret_cast<const float4*>(sp)[0];
        const float4 y = reinterpret_cast<const float4*>(sp)[1];
        v[0] = (__bf16)x.x; v[1] = (__bf16)x.y; v[2] = (__bf16)x.z; v[3] = (__bf16)x.w;
        v[4] = (__bf16)y.x; v[5] = (__bf16)y.y; v[6] = (__bf16)y.z; v[7] = (__bf16)y.w;
      } else {
#pragma unroll
        for (int k = 0; k < 8; ++k) v[k] = (__bf16)0.f;
      }
      *reinterpret_cast<bf16x8*>(sN + r * 256 + ((c * 16) ^ swz)) = v;
    }
  }
  __syncthreads();

  const int lane = tid & 63;
  const int l15 = lane & 15;
  const int hi = lane >> 4;
  const int hi16 = hi * 16;
  const int wvU = __builtin_amdgcn_readfirstlane(tid >> 6);

  float b0c[2][4];
#pragma unroll
  for (int nt = 0; nt < 2; ++nt)
#pragma unroll
    for (int r = 0; r < 4; ++r) b0c[nt][r] = b0[wvU * 32 + nt * 16 + hi * 4 + r];

#pragma unroll
  for (int pass = 0; pass < 2; ++pass) {
    const __bf16* Wt = pass ? W0wT : W0uT;
    __bf16* Tab = pass ? wTab : uTab;
    const bf16x8* wp = reinterpret_cast<const bf16x8*>(Wt);
    bf16x8 wf[4][2];
#pragma unroll
    for (int kk = 0; kk < 4; ++kk) {
      wf[kk][0] = wp[(wvU * 32 + l15) * 16 + kk * 4 + hi];
      wf[kk][1] = wp[(wvU * 32 + 16 + l15) * 16 + kk * 4 + hi];
    }
    floatx4 acc[4][2];
#pragma unroll
    for (int mt = 0; mt < 4; ++mt) { acc[mt][0] = (floatx4)0.f; acc[mt][1] = (floatx4)0.f; }
#pragma unroll
    for (int kk = 0; kk < 4; ++kk) {
#pragma unroll
      for (int mt = 0; mt < 4; ++mt) {
        const int row = mt * 16 + l15;
        const bf16x8 a = *reinterpret_cast<const bf16x8*>(
            sN + row * 256 + ((kk * 64 + hi16) ^ ((row & 7) << 4)));
        acc[mt][0] = mfma16x16x32(wf[kk][0], a, acc[mt][0]);
        acc[mt][1] = mfma16x16x32(wf[kk][1], a, acc[mt][1]);
      }
    }
#pragma unroll
    for (int mt = 0; mt < 4; ++mt) {
      const int node = base + mt * 16 + l15;
      if (node < nNodes) {
#pragma unroll
        for (int nt = 0; nt < 2; ++nt) {
          bf16x4 pk;
#pragma unroll
          for (int r = 0; r < 4; ++r) {
            const float v = acc[mt][nt][r] + (pass ? 0.f : b0c[nt][r]);
            pk[r] = (__bf16)v;
          }
          *reinterpret_cast<bf16x4*>(Tab + (size_t)node * 128 + wvU * 32 + nt * 16 +
                                     hi * 4) = pk;
        }
      }
    }
  }
}

// ---- edge kernel: 512 threads, 8 waves = 2M x 4N ----
__global__ __launch_bounds__(512, 2)
void edge_uw_kernel(const __bf16* __restrict__ uTab, const __bf16* __restrict__ wTab,
                    const int* __restrict__ srcI, const int* __restrict__ dstI,
                    const __bf16* __restrict__ W1T, const float* __restrict__ b1,
                    const float* __restrict__ W2, const float* __restrict__ b2,
                    float* __restrict__ out, int E, int nTiles) {
  // sUW: 2 x [64 edges][512B] (u-row 256B ++ w-row 256B), double-buffered,
  //      linear dest for global_load_lds; within each 256B half, logical 16B
  //      chunk j of row e stored at phys (j&8)|((j&7)^(e&7)); reads XOR byte
  //      offsets (<256) with (e&7)<<4.
  // sH : [64][128] bf16 rows of relu(u+w), 256B rows, same XOR swizzle.
  // sRed: overlay on head of consumed sUW[cur] (layer-2 partials, 1KB).
  __shared__ char sUW[2 * 64 * 512];
  __shared__ char sH[64 * 256];

  const int tid = threadIdx.x;
  const int lane = tid & 63;
  const int l15 = lane & 15;
  const int hi = lane >> 4;
  const int hi16 = hi * 16;
  const int wvU = __builtin_amdgcn_readfirstlane(tid >> 6);  // 0..7
  const int wm = wvU >> 2;       // M half: edges [32*wm, 32*wm+32)
  const int wn = wvU & 3;        // N quarter: cols [32*wn, 32*wn+32)
  const int wvByte = wvU * 4096; // 8 edges * 512B per wave (gather slice)

  // gather role: this wave stages edges [8*wvU, 8*wvU+8)
  const int lhalf = lane >> 5;          // which of 2 edges per issue
  const int p31 = lane & 31;            // phys 16B chunk within the 512B row
  const int half = (p31 >> 4) & 1;      // 0 -> u[src], 1 -> w[dst]
  const int* gIdxTab = half ? dstI : srcI;
  const __bf16* gTab = half ? wTab : uTab;

  // ---- per-wave register weights: W1T cols [32*wn, 32*wn+32) ----
  bf16x8 w1f[4][2];
  const bf16x8* w1p = reinterpret_cast<const bf16x8*>(W1T);
#pragma unroll
  for (int kk = 0; kk < 4; ++kk) {
    w1f[kk][0] = w1p[(wn * 32 + l15) * 16 + kk * 4 + hi];
    w1f[kk][1] = w1p[(wn * 32 + 16 + l15) * 16 + kk * 4 + hi];
  }
  float b1c[2][4], w2c[2][4];
#pragma unroll
  for (int nt = 0; nt < 2; ++nt)
#pragma unroll
    for (int r = 0; r < 4; ++r) {
      const int n = wn * 32 + nt * 16 + hi * 4 + r;
      b1c[nt][r] = b1[n];
      w2c[nt][r] = W2[n];
    }
  const float b2v = b2[0];

  const int tstride = gridDim.x;

  auto loadIdx = [&](int (&d)[4], int tt2) {
    const bool valid = tt2 < nTiles;
#pragma unroll
    for (int i = 0; i < 4; ++i) {
      const int eLoc = wvU * 8 + i * 2 + lhalf;
      const int ge = tt2 * 64 + eLoc;
      d[i] = (valid && ge < E) ? gIdxTab[ge] : 0;
    }
  };

  auto issueGather = [&](int nb, const int (&idx4)[4]) {
#pragma unroll
    for (int i = 0; i < 4; ++i) {
      const int eLoc = wvU * 8 + i * 2 + lhalf;
      const int wc = (p31 & 8) | ((p31 & 7) ^ (eLoc & 7));  // within-half chunk
      const __bf16* g = gTab + (size_t)idx4[i] * 128 + wc * 8;
      char* l = sUW + nb * 32768 + wvByte + i * 1024;  // + lane*16 added by HW
      __builtin_amdgcn_global_load_lds(
          (const __attribute__((address_space(1))) void*)g,
          (__attribute__((address_space(3))) void*)l, 16, 0, 0);
    }
  };

  // ---- prologue ----
  const int tile0 = blockIdx.x;
  int idxA[4], idxB[4];
  loadIdx(idxA, tile0);
  issueGather(0, idxA);
  loadIdx(idxB, tile0 + tstride);
  int cur = 0;

  for (int tt = tile0; tt < nTiles; tt += tstride) {
    __syncthreads();  // drains vmcnt: sUW[cur] ready; orders sH/sRed reuse

    // prefetch next tile's gathers (other buffer) + next-next indices
    if (tt + tstride < nTiles) issueGather(cur ^ 1, idxB);
    loadIdx(idxA, tt + 2 * tstride);

    const char* sUWc = sUW + cur * 32768;

    // ---- "layer 0": h = relu(u[src] + w[dst]) -> sH (2 chunk-pairs/thread) ----
    {
      const int aR = tid >> 3;            // row 0..63
      const int q = tid & 7;
      const int aswz = (aR & 7) << 4;
      const char* rowU = sUWc + aR * 512;
      char* rowH = sH + aR * 256;
#pragma unroll
      for (int ii = 0; ii < 2; ++ii) {
        const int c = q * 2 + ii;         // 16B chunk 0..15
        const int off = (c * 16) ^ aswz;
        const bf16x8 uu = *reinterpret_cast<const bf16x8*>(rowU + off);
        const bf16x8 ww = *reinterpret_cast<const bf16x8*>(rowU + 256 + off);
        bf16x8 hh;
#pragma unroll
        for (int k = 0; k < 8; ++k)
          hh[k] = (__bf16)fmaxf((float)uu[k] + (float)ww[k], 0.0f);
        *reinterpret_cast<bf16x8*>(rowH + off) = hh;
      }
    }
    bar_lds();  // B2: sUW[cur] consumed, sH visible

    // ---- layer 1 (swapped): this wave's 32 edges x 32 cols ----
    floatx4 acc2T[2][2];
#pragma unroll
    for (int mt = 0; mt < 2; ++mt) { acc2T[mt][0] = (floatx4)0.f; acc2T[mt][1] = (floatx4)0.f; }
#pragma unroll
    for (int kk = 0; kk < 4; ++kk) {
#pragma unroll
      for (int mt = 0; mt < 2; ++mt) {
        const int row = wm * 32 + mt * 16 + l15;
        const bf16x8 a = *reinterpret_cast<const bf16x8*>(
            sH + row * 256 + ((kk * 64 + hi16) ^ ((row & 7) << 4)));
        acc2T[mt][0] = mfma16x16x32(w1f[kk][0], a, acc2T[mt][0]);
        acc2T[mt][1] = mfma16x16x32(w1f[kk][1], a, acc2T[mt][1]);
      }
    }

    // ---- layer 2: per-lane dot over 8 n, reduce across hi groups ----
    float* sRedF = (float*)sUWc;  // overlay on consumed sUW[cur]
#pragma unroll
    for (int mt = 0; mt < 2; ++mt) {
      float pp = 0.f;
#pragma unroll
      for (int nt = 0; nt < 2; ++nt)
#pragma unroll
        for (int r = 0; r < 4; ++r)
          pp += fmaxf(acc2T[mt][nt][r] + b1c[nt][r], 0.0f) * w2c[nt][r];
      pp += __shfl_xor(pp, 16);
      pp += __shfl_xor(pp, 32);
      if (lane < 16) sRedF[(wm * 32 + mt * 16 + l15) * 4 + wn] = pp;
    }
    bar_lds();  // B3: partials visible

    if (tid < 64) {
      const int ge = tt * 64 + tid;
      if (ge < E) {
        const float4 v = reinterpret_cast<const float4*>(sRedF)[tid];
        out[ge] = v.x + v.y + v.z + v.w + b2v;
      }
    }

#pragma unroll
    for (int i = 0; i < 4; ++i) idxB[i] = idxA[i];
    cur ^= 1;
  }
}

// ---- correctness fallback (only if workspace too small) ----
__global__ void edge_mlp_fallback(const float* __restrict__ h1, const float* __restrict__ h2,
                                  const int* __restrict__ src, const int* __restrict__ dst,
                                  const float* __restrict__ W0, const float* __restrict__ b0,
                                  const float* __restrict__ W1, const float* __restrict__ b1,
                                  const float* __restrict__ W2, const float* __restrict__ b2,
                                  float* __restrict__ out, int E) {
  __shared__ float sa[256];
  __shared__ float sh[128];
  __shared__ float sr[128];
  const int e = blockIdx.x;
  if (e >= E) return;
  const int t = threadIdx.x;  // 128 threads
  const int is = src[e], id = dst[e];
  if (t < 64) { sa[t] = h1[is * 64 + t]; sa[128 + t] = h2[is * 64 + t]; }
  else { const int u = t - 64; sa[64 + u] = h1[id * 64 + u]; sa[192 + u] = h2[id * 64 + u]; }
  __syncthreads();
  float a0 = b0[t];
  for (int k = 0; k < 256; ++k) a0 += sa[k] * W0[k * 128 + t];
  sh[t] = fmaxf(a0, 0.f);
  __syncthreads();
  float a1 = b1[t];
  for (int k = 0; k < 128; ++k) a1 += sh[k] * W1[k * 128 + t];
  sr[t] = fmaxf(a1, 0.f) * W2[t];
  __syncthreads();
  if (t == 0) {
    float s = b2[0];
    for (int k = 0; k < 128; ++k) s += sr[k];
    out[e] = s;
  }
}

extern "C" void kernel_launch(void* const* d_in, const int* in_sizes, int n_in,
                              void* d_out, int out_size, void* d_ws, size_t ws_size,
                              hipStream_t stream) {
  const float* h1 = (const float*)d_in[0];
  const float* h2 = (const float*)d_in[1];
  const int* src = (const int*)d_in[2];
  const int* dst = (const int*)d_in[3];
  const float* W0 = (const float*)d_in[4];
  const float* b0 = (const float*)d_in[5];
  const float* W1 = (const float*)d_in[6];
  const float* b1 = (const float*)d_in[7];
  const float* W2 = (const float*)d_in[8];
  const float* b2 = (const float*)d_in[9];
  float* out = (float*)d_out;

  const int D = 64;
  const int nNodes = in_sizes[0] / D;
  const int E = in_sizes[2];

  char* ws = (char*)d_ws;
  __bf16* W1T = (__bf16*)(ws);                 // 32768 B
  __bf16* W0uT = (__bf16*)(ws + 32768);        // 32768 B
  __bf16* W0wT = (__bf16*)(ws + 65536);        // 32768 B
  const size_t tabBytes = (size_t)nNodes * 128 * sizeof(__bf16);
  __bf16* uTab = (__bf16*)(ws + 98304);
  __bf16* wTab = (__bf16*)(ws + 98304 + tabBytes);
  const bool useFast = ws_size >= 98304 + 2 * tabBytes;

  if (!useFast) {
    edge_mlp_fallback<<<dim3(E), dim3(128), 0, stream>>>(
        h1, h2, src, dst, W0, b0, W1, b1, W2, b2, out, E);
    return;
  }

  cvt_w_kernel<<<dim3(192), dim3(256), 0, stream>>>(W0, W1, W1T, W0uT, W0wT);
  node_uw_kernel<<<dim3((nNodes + 63) / 64), dim3(256), 0, stream>>>(
      h1, h2, W0uT, W0wT, b0, uTab, wTab, nNodes);

  const int nTiles = (E + 63) / 64;
  const int grid = nTiles < 512 ? nTiles : 512;  // 2 blocks/CU resident
  edge_uw_kernel<<<dim3(grid), dim3(512), 0, stream>>>(
      uTab, wTab, src, dst, W1T, b1, W2, b2, out, E, nTiles);
}